// Round 6
// baseline (4033.874 us; speedup 1.0000x reference)
//
#include <hip/hip_runtime.h>
#include <math.h>

#define BB 16
#define TT 500
#define CC 2048
#define SN 64
#define SD 512
#define NGRP 16         // den groups (1 batch each)
#define NCB 8           // column blocks of 64 per group
#define NDEN 128        // 16 * 8
#define NTHR 512
#define SHIFTC 30.0f

// ws layout (unchanged from round 0/4 — known-safe footprint 131328 B):
//   bytes [0, 131072): u64 pg[2][16][512] -- (tag<<32)|float_bits
//   float index 32768+: DACC[16], DSCALE[16], NACC[16], NSCALE[16]
#define WSF_DACC   32768
#define WSF_DSCALE 32784
#define WSF_NACC   32800
#define WSF_NSCALE 32816

#define AL(p) __hip_atomic_load((p), __ATOMIC_RELAXED, __HIP_MEMORY_SCOPE_AGENT)
#define AS(p, v) __hip_atomic_store((p), (v), __ATOMIC_RELAXED, __HIP_MEMORY_SCOPE_AGENT)

typedef float f4 __attribute__((ext_vector_type(4)));

// L2 poll load: sc0 bypasses L1 (no invalidation protocol) and reads the
// XCD-shared L2. Stores remain AGENT-scope (write-through past L2), so:
//  - same-XCD consumer: sc0 read sees the line updated/refilled fast (~L2 RT)
//  - any stale/bypass semantics: tag mismatch -> budgeted spin -> agent
//    fallback below, which is the round-4-proven path. No hang possible.
__device__ __forceinline__ unsigned long long ld_l2(const unsigned long long* p) {
  unsigned long long r;
  asm volatile("global_load_dwordx2 %0, %1, off sc0\n\t"
               "s_waitcnt vmcnt(0)"
               : "=v"(r)
               : "v"((unsigned long long)p)
               : "memory");
  return r;
}

__device__ __forceinline__ float wave_max(float v) {
  #pragma unroll
  for (int off = 32; off > 0; off >>= 1) v = fmaxf(v, __shfl_xor(v, off, 64));
  return v;
}
__device__ __forceinline__ float wave_sum(float v) {
  #pragma unroll
  for (int off = 32; off > 0; off >>= 1) v += __shfl_xor(v, off, 64);
  return v;
}
__device__ __forceinline__ unsigned long long pk(unsigned tag, float v) {
  return ((unsigned long long)tag << 32) | (unsigned long long)__float_as_uint(v);
}
__device__ __forceinline__ float clamp30(float v) {
  return fminf(fmaxf(v, -30.f), 30.f);
}
__device__ __forceinline__ float rlane(float v, int k) {
  return __uint_as_float(__builtin_amdgcn_readlane(__float_as_uint(v), k));
}

// LDS-only barrier: __syncthreads() drains vmcnt(0) (kills in-flight global
// prefetches); LDS producer/consumer ordering needs only lgkmcnt + s_barrier.
__device__ __forceinline__ void barrier_lds_only() {
  asm volatile("s_waitcnt lgkmcnt(0)" ::: "memory");
  __builtin_amdgcn_s_barrier();
  asm volatile("" ::: "memory");
}

__global__ __launch_bounds__(NTHR, 1) void fsm_fwd(
    const float* __restrict__ x, const int* __restrict__ seqlens,
    const float* __restrict__ nA, const float* __restrict__ nls,
    const float* __restrict__ nlf, const int* __restrict__ npdf,
    const float* __restrict__ dA, const float* __restrict__ dls,
    const float* __restrict__ dlf, const int* __restrict__ dpdf,
    unsigned long long* __restrict__ p64, float* __restrict__ wsf)
{
  __shared__ float prt[2][8 * 64];   // double-buffered per-wave partial q
  __shared__ float pmx[2][8];        // double-buffered per-wave chunk maxes
  const int tid = threadIdx.x;
  const int lane = tid & 63, wv = tid >> 6;

  if (blockIdx.x < NDEN) {
    // ---------------- DEN (shared A, S=512), 1 batch per group --------------
    // g = bid & 15 keeps all 8 column-block WGs of a group at the same
    // (bid % 8) => same XCD under round-robin dispatch => sc0 polls hit the
    // shared L2. This is a PERFORMANCE heuristic only: correctness/liveness
    // never depend on it (agent fallback below).
    const int g  = blockIdx.x & 15;     // group == batch
    const int cb = blockIdx.x >> 4;     // column block (0..7)
    const int j0 = cb * 64;

    // A in registers: lane holds exp(A[i0+k][j0+lane]) for its wave's i-window
    f4 Areg[16];
    {
      const float* Ap = dA + (wv * 64) * SD + j0 + lane;
      #pragma unroll
      for (int k = 0; k < 64; ++k)
        Areg[k >> 2][k & 3] = __expf(Ap[k * SD]);
      #pragma unroll
      for (int r = 0; r < 16; ++r)
        asm volatile("" : "+v"(Areg[r]));   // keep resident across the loop
    }

    unsigned long long* gb0 = p64 + (size_t)g * SD;              // buf 0
    unsigned long long* gb1 = p64 + (size_t)(NGRP + g) * SD;     // buf 1

    // wave 0 owns the epilogue state for this WG's 64 columns
    int pdfj = 0, sl = 0; float lfj = 0.f, pcur = 0.f, scale = SHIFTC;
    float xc = 0.f;                       // emission for current step t
    if (wv == 0) {
      pdfj = dpdf[j0 + lane];
      lfj  = dlf[j0 + lane];
      sl   = seqlens[g];
      float xv = clamp30(x[g * (TT * CC) + pdfj]);
      pcur = __expf(dls[j0 + lane] + xv - SHIFTC);
      AS(gb0 + j0 + lane, pk(0u, pcur));
      xc = clamp30(x[g * (TT * CC) + CC + pdfj]);   // prefetch t=1 emission
    }

    int budget = 48;   // sc0 spins before agent fallback (per lane)
    int miss4  = 0;    // consecutive budget exhaustions -> disable sc0

    for (int t = 1; t < TT; ++t) {
      unsigned long long* gin  = (t & 1) ? gb0 : gb1;
      unsigned long long* gout = (t & 1) ? gb1 : gb0;

      // poll own chunk: wave wv consumes producer WG cb==wv's 64 words
      const unsigned tg = (unsigned)(t - 1);
      unsigned long long* pa = gin + wv * 64 + lane;
      unsigned long long w = 0;
      bool got = false;
      for (int s = 0; s < budget; ++s) {        // fast path: L2 (sc0) poll
        w = ld_l2(pa);
        if ((unsigned)(w >> 32) == tg) { got = true; break; }
        __builtin_amdgcn_s_sleep(1);
      }
      if (!got) {
        for (;;) {                              // proven agent-scope fallback
          w = AL(pa);
          if ((unsigned)(w >> 32) == tg) break;
          __builtin_amdgcn_s_sleep(1);
        }
        if (++miss4 >= 4) budget = 0;           // sc0 never works here: stop
      } else {
        miss4 = 0;
      }
      float pv = __uint_as_float((unsigned)w);

      // chunk max for the lagged renormalizer
      float cm = wave_max(pv);
      if (lane == 0) pmx[t & 1][wv] = cm;

      // matvec over own i-window: broadcast p via v_readlane (pure VALU)
      float q = 0.f;
      #pragma unroll
      for (int k = 0; k < 64; ++k) {
        float pk_ = rlane(pv, k);
        q = fmaf(pk_, Areg[k >> 2][k & 3], q);
      }
      prt[t & 1][wv * 64 + lane] = q;

      barrier_lds_only();   // LDS-ordering only; keeps global loads in flight

      if (wv == 0) {
        const float* pb = prt[t & 1];
        float qq = 0.f;
        #pragma unroll
        for (int w8 = 0; w8 < 8; ++w8) qq += pb[w8 * 64 + lane];
        float m = pmx[t & 1][0];
        #pragma unroll
        for (int w8 = 1; w8 < 8; ++w8) m = fmaxf(m, pmx[t & 1][w8]);
        float lm = __logf(m);
        if (t < sl) {
          pcur = qq * __expf(xc - SHIFTC - lm);
          scale += SHIFTC + lm;
        }
        AS(gout + j0 + lane, pk((unsigned)t, pcur));  // agent: MALL-visible
        if (t + 1 < TT)                  // emission prefetch, ~1 step of slack
          xc = clamp30(x[g * (TT * CC) + (t + 1) * CC + pdfj]);
      }
    }
    if (wv == 0) {
      float part = wave_sum(pcur * __expf(lfj));
      if (lane == 0) {
        atomicAdd(wsf + WSF_DACC + g, part);
        if (cb == 0) wsf[WSF_DSCALE + g] = scale;
      }
    }
  } else {
    // ---------------- NUM (per-batch A, S=64), single wave, pure VALU -------
    const int b = blockIdx.x - NDEN;
    if (wv != 0) return;

    f4 Areg[16];   // lane holds exp(nA[i][lane]) for all i
    {
      const float* Ap = nA + b * SN * SN + lane;
      #pragma unroll
      for (int i = 0; i < 64; ++i)
        Areg[i >> 2][i & 3] = __expf(Ap[i * SN]);
      #pragma unroll
      for (int r = 0; r < 16; ++r)
        asm volatile("" : "+v"(Areg[r]));
    }
    const int   pdfj = npdf[b * SN + lane];
    const float lfj  = nlf[b * SN + lane];
    const int   sl   = seqlens[b];
    float xv0 = clamp30(x[b * (TT * CC) + pdfj]);
    float pcur = __expf(nls[b * SN + lane] + xv0 - SHIFTC);
    float scale = SHIFTC;
    float xn = clamp30(x[b * (TT * CC) + CC + pdfj]);   // prefetch t=1

    for (int t = 1; t < TT; ++t) {
      float xv = xn;
      if (t + 1 < TT)
        xn = clamp30(x[b * (TT * CC) + (t + 1) * CC + pdfj]);
      float pold = pcur;
      float q = 0.f;
      #pragma unroll
      for (int i = 0; i < 64; ++i) {
        float pi = rlane(pold, i);
        q = fmaf(pi, Areg[i >> 2][i & 3], q);
      }
      float lm = __logf(wave_max(pold));
      if (t < sl) {
        pcur = q * __expf(xv - SHIFTC - lm);
        scale += SHIFTC + lm;
      }
    }
    float part = wave_sum(pcur * __expf(lfj));
    if (lane == 0) {
      wsf[WSF_NACC + b]   = part;
      wsf[WSF_NSCALE + b] = scale;
    }
  }
}

__global__ void fsm_final(const float* __restrict__ wsf, float* __restrict__ out) {
  const int tid = threadIdx.x;
  float v = 0.f;
  if (tid < 16)
    v = -(wsf[WSF_NSCALE + tid] + __logf(wsf[WSF_NACC + tid]));
  else if (tid < 32)
    v = (wsf[WSF_DSCALE + tid - 16] + __logf(wsf[WSF_DACC + tid - 16]));
  v = wave_sum(v);
  if (tid == 0) out[0] = v;  // loss = den_sum - num_sum
}

extern "C" void kernel_launch(void* const* d_in, const int* in_sizes, int n_in,
                              void* d_out, int out_size, void* d_ws, size_t ws_size,
                              hipStream_t stream) {
  const float* x    = (const float*)d_in[0];
  const int*   sql  = (const int*)d_in[1];
  const float* nA   = (const float*)d_in[2];
  const float* nls  = (const float*)d_in[3];
  const float* nlf  = (const float*)d_in[4];
  const int*   npdf = (const int*)d_in[5];
  const float* dA   = (const float*)d_in[6];
  const float* dls  = (const float*)d_in[7];
  const float* dlf  = (const float*)d_in[8];
  const int*   dpdf = (const int*)d_in[9];
  float* out = (float*)d_out;
  unsigned long long* p64 = (unsigned long long*)d_ws;
  float* wsf = (float*)d_ws;
  (void)in_sizes; (void)n_in; (void)out_size; (void)ws_size;

  // zero only the accumulators (known-safe 256 B); the tagged exchange
  // region relies on tag monotonicity, no reset needed.
  hipMemsetAsync((char*)d_ws + 131072, 0, 256, stream);
  fsm_fwd<<<NDEN + BB, NTHR, 0, stream>>>(x, sql, nA, nls, nlf, npdf,
                                          dA, dls, dlf, dpdf, p64, wsf);
  fsm_final<<<1, 64, 0, stream>>>(wsf, out);
}

// Round 7
// 2922.069 us; speedup vs baseline: 1.3805x; 1.3805x over previous
//
#include <hip/hip_runtime.h>
#include <math.h>

#define BB 16
#define TT 500
#define CC 2048
#define SN 64
#define SD 512
#define NGRP 16
#define NSETS 4         // den WG-sets; set s owns groups 4s..4s+3
#define GPW 4           // groups per set, time-multiplexed as 4 phases
#define NDENSLOT 64     // launched den slots; active iff (bid&7)<NSETS (32 WGs)
#define NTHR 512
#define SHIFTC 30.0f

// ws layout (unchanged, known-safe 131328 B):
//   bytes [0, 131072): u64 pg[2][16][512] -- (tag<<32)|float_bits
//   float index 32768+: DACC[16], DSCALE[16], NACC[16], NSCALE[16]
#define WSF_DACC   32768
#define WSF_DSCALE 32784
#define WSF_NACC   32800
#define WSF_NSCALE 32816

#define AL(p) __hip_atomic_load((p), __ATOMIC_RELAXED, __HIP_MEMORY_SCOPE_AGENT)
#define AS(p, v) __hip_atomic_store((p), (v), __ATOMIC_RELAXED, __HIP_MEMORY_SCOPE_AGENT)

typedef float f4 __attribute__((ext_vector_type(4)));

__device__ __forceinline__ float wave_max(float v) {
  #pragma unroll
  for (int off = 32; off > 0; off >>= 1) v = fmaxf(v, __shfl_xor(v, off, 64));
  return v;
}
__device__ __forceinline__ float wave_sum(float v) {
  #pragma unroll
  for (int off = 32; off > 0; off >>= 1) v += __shfl_xor(v, off, 64);
  return v;
}
__device__ __forceinline__ unsigned long long pk(unsigned tag, float v) {
  return ((unsigned long long)tag << 32) | (unsigned long long)__float_as_uint(v);
}
__device__ __forceinline__ float clamp30(float v) {
  return fminf(fmaxf(v, -30.f), 30.f);
}
__device__ __forceinline__ float rlane(float v, int k) {
  return __uint_as_float(__builtin_amdgcn_readlane(__float_as_uint(v), k));
}
// record holding tag T for group g lives at slot (T&1)
__device__ __forceinline__ unsigned long long* recbase(
    unsigned long long* p64, int g, int tag) {
  return p64 + ((tag & 1) ? (size_t)(NGRP + g) : (size_t)g) * SD;
}

// LDS-only barrier: __syncthreads() drains vmcnt(0), which would serialize
// our in-flight MALL poll/emission prefetches into every phase. LDS
// producer/consumer ordering needs only lgkmcnt + s_barrier.
__device__ __forceinline__ void barrier_lds_only() {
  asm volatile("s_waitcnt lgkmcnt(0)" ::: "memory");
  __builtin_amdgcn_s_barrier();
  asm volatile("" ::: "memory");
}

__global__ __launch_bounds__(NTHR, 1) void fsm_fwd(
    const float* __restrict__ x, const int* __restrict__ seqlens,
    const float* __restrict__ nA, const float* __restrict__ nls,
    const float* __restrict__ nlf, const int* __restrict__ npdf,
    const float* __restrict__ dA, const float* __restrict__ dls,
    const float* __restrict__ dlf, const int* __restrict__ dpdf,
    unsigned long long* __restrict__ p64, float* __restrict__ wsf)
{
  __shared__ float prt[2][8][64];   // [phase parity][row-window wave][col]
  __shared__ float pmx[2][8];       // [phase parity][row-window wave]
  const int tid = threadIdx.x;
  const int lane = tid & 63, wv = tid >> 6;

  if (blockIdx.x < NDENSLOT) {
    if ((blockIdx.x & 7) >= NSETS) return;   // inactive filler slot
    // ---- DEN: set s = bid&7 (== XCD under round-robin), cb = bid>>3 -------
    // 4 groups (4s..4s+3) time-multiplexed as 4 phases per t. Consumption of
    // a record happens 3 phases after its production -> MALL store-visibility
    // latency V is hidden by other groups' compute.
    const int st = blockIdx.x & 7;
    const int cb = blockIdx.x >> 3;
    const int j0 = cb * 64;
    const int gbase = st * GPW;

    // A-window in registers: lane holds exp(A[wv*64+k][j0+lane])
    f4 Areg[16];
    {
      const float* Ap = dA + (wv * 64) * SD + j0 + lane;
      #pragma unroll
      for (int k = 0; k < 64; ++k)
        Areg[k >> 2][k & 3] = __expf(Ap[k * SD]);
      #pragma unroll
      for (int r = 0; r < 16; ++r)
        asm volatile("" : "+v"(Areg[r]));
    }

    // owner-column constants: wave w's lanes 0..7 own columns j0+8w..j0+8w+7
    const int oc   = j0 + 8 * wv + (lane & 7);    // owner column (lane<8)
    const int pdfo = dpdf[oc];
    const float lfo = dlf[oc];
    const float lso = dls[oc];

    int   sl4[GPW];
    float pc[GPW], sc[GPW];
    #pragma unroll
    for (int gk = 0; gk < GPW; ++gk) {
      const int g = gbase + gk;
      sl4[gk] = seqlens[g];
      sc[gk]  = SHIFTC;
      pc[gk]  = 0.f;
      if (lane < 8) {
        float xv = clamp30(x[(size_t)g * (TT * CC) + pdfo]);
        pc[gk] = __expf(lso + xv - SHIFTC);
        AS(recbase(p64, g, 0) + oc, pk(0u, pc[gk]));
      }
    }
    // prime the rotating prefetches for phase (gk=0, t=1)
    unsigned long long pf = AL(recbase(p64, gbase, 0) + wv * 64 + lane);
    float xn = 0.f;
    if (lane < 8)
      xn = clamp30(x[(size_t)gbase * (TT * CC) + CC + pdfo]);

    for (int t = 1; t < TT; ++t) {
      #pragma unroll
      for (int gk = 0; gk < GPW; ++gk) {
        const int g   = gbase + gk;
        const int par = gk & 1;               // adjacent phases alternate
        const unsigned tg = (unsigned)(t - 1);
        unsigned long long* pa = recbase(p64, g, t - 1) + wv * 64 + lane;

        // poll: first check the prefetched register (data is ~4 phases old
        // in steady state -> usually visible); fall back to agent spin.
        unsigned long long w = pf;
        while ((unsigned)(w >> 32) != tg) {
          w = AL(pa);
          if ((unsigned)(w >> 32) == tg) break;
          __builtin_amdgcn_s_sleep(1);
        }
        float pv = __uint_as_float((unsigned)w);

        float cm = wave_max(pv);
        if (lane == 0) pmx[par][wv] = cm;

        float q = 0.f;
        #pragma unroll
        for (int k = 0; k < 64; ++k)
          q = fmaf(rlane(pv, k), Areg[k >> 2][k & 3], q);
        prt[par][wv][lane] = q;

        // rotate prefetches for the NEXT phase (stay in flight across the
        // drain-free barrier)
        const int  gn = (gk == GPW - 1) ? gbase : g + 1;
        const int  tn = (gk == GPW - 1) ? t + 1 : t;
        const bool hn = (tn < TT);
        float xq = xn;
        if (hn) {
          pf = AL(recbase(p64, gn, tn - 1) + wv * 64 + lane);
          if (lane < 8)
            xn = clamp30(x[(size_t)gn * (TT * CC) + (size_t)tn * CC + pdfo]);
        }

        barrier_lds_only();   // LDS ordering only; global loads keep flying

        // distributed epilogue: wave wv's lanes 0..7 handle cols 8wv..8wv+7.
        // Serial ascending adds/maxes => bitwise-identical to the round-0
        // wave0 epilogue for the same column.
        if (lane < 8) {
          float m = pmx[par][0];
          #pragma unroll
          for (int w8 = 1; w8 < 8; ++w8) m = fmaxf(m, pmx[par][w8]);
          float lm = __logf(m);
          float qq = 0.f;
          #pragma unroll
          for (int w8 = 0; w8 < 8; ++w8) qq += prt[par][w8][8 * wv + lane];
          if (t < sl4[gk]) {
            pc[gk] = qq * __expf(xq - SHIFTC - lm);
            sc[gk] += SHIFTC + lm;
          }
          AS(recbase(p64, g, t) + oc, pk((unsigned)t, pc[gk]));
        }
      }
    }

    // final reduction: each wave sums its 8 owner columns (lanes>=8 add 0)
    #pragma unroll
    for (int gk = 0; gk < GPW; ++gk) {
      const int g = gbase + gk;
      float v = (lane < 8) ? pc[gk] * __expf(lfo) : 0.f;
      float part = wave_sum(v);
      if (lane == 0)
        atomicAdd(wsf + WSF_DACC + g, part);
    }
    if (cb == 0 && wv == 0 && lane == 0) {
      #pragma unroll
      for (int gk = 0; gk < GPW; ++gk)
        wsf[WSF_DSCALE + gbase + gk] = sc[gk];
    }
  } else {
    // ---------------- NUM (per-batch A, S=64), single wave, pure VALU -------
    const int b = blockIdx.x - NDENSLOT;
    if (wv != 0) return;

    f4 Areg[16];   // lane holds exp(nA[i][lane]) for all i
    {
      const float* Ap = nA + b * SN * SN + lane;
      #pragma unroll
      for (int i = 0; i < 64; ++i)
        Areg[i >> 2][i & 3] = __expf(Ap[i * SN]);
      #pragma unroll
      for (int r = 0; r < 16; ++r)
        asm volatile("" : "+v"(Areg[r]));
    }
    const int   pdfj = npdf[b * SN + lane];
    const float lfj  = nlf[b * SN + lane];
    const int   sl   = seqlens[b];
    float xv0 = clamp30(x[(size_t)b * (TT * CC) + pdfj]);
    float pcur = __expf(nls[b * SN + lane] + xv0 - SHIFTC);
    float scale = SHIFTC;
    float xnn = clamp30(x[(size_t)b * (TT * CC) + CC + pdfj]);

    for (int t = 1; t < TT; ++t) {
      float xv = xnn;
      if (t + 1 < TT)
        xnn = clamp30(x[(size_t)b * (TT * CC) + (size_t)(t + 1) * CC + pdfj]);
      float pold = pcur;
      float q = 0.f;
      #pragma unroll
      for (int i = 0; i < 64; ++i) {
        float pi = rlane(pold, i);
        q = fmaf(pi, Areg[i >> 2][i & 3], q);
      }
      float lm = __logf(wave_max(pold));
      if (t < sl) {
        pcur = q * __expf(xv - SHIFTC - lm);
        scale += SHIFTC + lm;
      }
    }
    float part = wave_sum(pcur * __expf(lfj));
    if (lane == 0) {
      wsf[WSF_NACC + b]   = part;
      wsf[WSF_NSCALE + b] = scale;
    }
  }
}

__global__ void fsm_final(const float* __restrict__ wsf, float* __restrict__ out) {
  const int tid = threadIdx.x;
  float v = 0.f;
  if (tid < 16)
    v = -(wsf[WSF_NSCALE + tid] + __logf(wsf[WSF_NACC + tid]));
  else if (tid < 32)
    v = (wsf[WSF_DSCALE + tid - 16] + __logf(wsf[WSF_DACC + tid - 16]));
  v = wave_sum(v);
  if (tid == 0) out[0] = v;  // loss = den_sum - num_sum
}

extern "C" void kernel_launch(void* const* d_in, const int* in_sizes, int n_in,
                              void* d_out, int out_size, void* d_ws, size_t ws_size,
                              hipStream_t stream) {
  const float* x    = (const float*)d_in[0];
  const int*   sql  = (const int*)d_in[1];
  const float* nA   = (const float*)d_in[2];
  const float* nls  = (const float*)d_in[3];
  const float* nlf  = (const float*)d_in[4];
  const int*   npdf = (const int*)d_in[5];
  const float* dA   = (const float*)d_in[6];
  const float* dls  = (const float*)d_in[7];
  const float* dlf  = (const float*)d_in[8];
  const int*   dpdf = (const int*)d_in[9];
  float* out = (float*)d_out;
  unsigned long long* p64 = (unsigned long long*)d_ws;
  float* wsf = (float*)d_ws;
  (void)in_sizes; (void)n_in; (void)out_size; (void)ws_size;

  // zero only the accumulators; tagged region relies on tag monotonicity
  hipMemsetAsync((char*)d_ws + 131072, 0, 256, stream);
  fsm_fwd<<<NDENSLOT + BB, NTHR, 0, stream>>>(x, sql, nA, nls, nlf, npdf,
                                              dA, dls, dlf, dpdf, p64, wsf);
  fsm_final<<<1, 64, 0, stream>>>(wsf, out);
}

// Round 8
// 1353.965 us; speedup vs baseline: 2.9793x; 2.1582x over previous
//
#include <hip/hip_runtime.h>
#include <math.h>

#define BB 16
#define TT 500
#define CC 2048
#define SN 64
#define SD 512
#define NGRP 16         // den groups (1 batch each)
#define NCB 8           // column blocks of 64 per group
#define NDEN 128        // 16 * 8
#define NTHR 512
#define SHIFTC 30.0f
#define SC0_BUDGET 8    // fast-path (L2) poll tries before agent fallback

// ws layout (unchanged, known-safe footprint 131328 B):
//   bytes [0, 131072): u64 pg[2][16][512] -- (tag<<32)|float_bits
//   float index 32768+: DACC[16], DSCALE[16], NACC[16], NSCALE[16]
#define WSF_DACC   32768
#define WSF_DSCALE 32784
#define WSF_NACC   32800
#define WSF_NSCALE 32816

#define AL(p) __hip_atomic_load((p), __ATOMIC_RELAXED, __HIP_MEMORY_SCOPE_AGENT)
#define AS(p, v) __hip_atomic_store((p), (v), __ATOMIC_RELAXED, __HIP_MEMORY_SCOPE_AGENT)

typedef float f4 __attribute__((ext_vector_type(4)));

// FAST exchange ops (same-XCD): sc0 store = write-through L1, lands in the
// shared XCD L2 (round 6 proved sc1 stores do NOT refresh L2 -- every sc1
// poll pays a MALL RT). sc0 load = bypass L1, read that L2. RT ~250cy vs
// ~2500cy. Liveness never depends on these: the producer ALSO issues the
// round-0-proven agent store of the SAME bits (below), and the consumer
// falls back to the round-0-proven agent poll on budget exhaustion.
__device__ __forceinline__ unsigned long long ld_sc0(const unsigned long long* p) {
  unsigned long long r;
  asm volatile("global_load_dwordx2 %0, %1, off sc0\n\t"
               "s_waitcnt vmcnt(0)"
               : "=v"(r) : "v"((unsigned long long)p) : "memory");
  return r;
}
__device__ __forceinline__ void st_sc0(unsigned long long* p, unsigned long long v) {
  asm volatile("global_store_dwordx2 %0, %1, off sc0"
               :: "v"((unsigned long long)p), "v"(v) : "memory");
}

__device__ __forceinline__ float wave_max(float v) {
  #pragma unroll
  for (int off = 32; off > 0; off >>= 1) v = fmaxf(v, __shfl_xor(v, off, 64));
  return v;
}
__device__ __forceinline__ float wave_sum(float v) {
  #pragma unroll
  for (int off = 32; off > 0; off >>= 1) v += __shfl_xor(v, off, 64);
  return v;
}
__device__ __forceinline__ unsigned long long pk(unsigned tag, float v) {
  return ((unsigned long long)tag << 32) | (unsigned long long)__float_as_uint(v);
}
__device__ __forceinline__ float clamp30(float v) {
  return fminf(fmaxf(v, -30.f), 30.f);
}
__device__ __forceinline__ float rlane(float v, int k) {
  return __uint_as_float(__builtin_amdgcn_readlane(__float_as_uint(v), k));
}

// LDS-only barrier: __syncthreads() drains vmcnt(0), serializing in-flight
// global prefetches; LDS ordering needs only lgkmcnt + s_barrier.
__device__ __forceinline__ void barrier_lds_only() {
  asm volatile("s_waitcnt lgkmcnt(0)" ::: "memory");
  __builtin_amdgcn_s_barrier();
  asm volatile("" ::: "memory");
}

__global__ __launch_bounds__(NTHR, 1) void fsm_fwd(
    const float* __restrict__ x, const int* __restrict__ seqlens,
    const float* __restrict__ nA, const float* __restrict__ nls,
    const float* __restrict__ nlf, const int* __restrict__ npdf,
    const float* __restrict__ dA, const float* __restrict__ dls,
    const float* __restrict__ dlf, const int* __restrict__ dpdf,
    unsigned long long* __restrict__ p64, float* __restrict__ wsf)
{
  __shared__ float prt[2][8 * 64];   // double-buffered per-wave partial q
  __shared__ float pmx[2][8];        // double-buffered per-wave chunk maxes
  const int tid = threadIdx.x;
  const int lane = tid & 63, wv = tid >> 6;

  if (blockIdx.x < NDEN) {
    // ---------------- DEN (shared A, S=512), 1 batch per group --------------
    // g = bid & 15 keeps all 8 column-block WGs of a group at the same
    // (bid % 8) => same XCD under round-robin dispatch => sc0 exchange hits
    // the shared L2. Performance heuristic only: dual-store + agent fallback
    // keep correctness/liveness placement-independent.
    const int g  = blockIdx.x & 15;     // group == batch
    const int cb = blockIdx.x >> 4;     // column block (0..7)
    const int j0 = cb * 64;

    // A in registers: lane holds exp(A[i0+k][j0+lane]) for its wave's i-window
    f4 Areg[16];
    {
      const float* Ap = dA + (wv * 64) * SD + j0 + lane;
      #pragma unroll
      for (int k = 0; k < 64; ++k)
        Areg[k >> 2][k & 3] = __expf(Ap[k * SD]);
      #pragma unroll
      for (int r = 0; r < 16; ++r)
        asm volatile("" : "+v"(Areg[r]));
    }

    unsigned long long* gb0 = p64 + (size_t)g * SD;              // buf 0
    unsigned long long* gb1 = p64 + (size_t)(NGRP + g) * SD;     // buf 1

    // wave 0 owns the epilogue state for this WG's 64 columns
    int pdfj = 0, sl = 0; float lfj = 0.f, pcur = 0.f, scale = SHIFTC;
    float xraw = 0.f;                      // RAW emission bits (clamp at use!)
    if (wv == 0) {
      pdfj = dpdf[j0 + lane];
      lfj  = dlf[j0 + lane];
      sl   = seqlens[g];
      float xv = clamp30(x[g * (TT * CC) + pdfj]);
      pcur = __expf(dls[j0 + lane] + xv - SHIFTC);
      unsigned long long rec = pk(0u, pcur);
      unsigned long long* gp = gb0 + j0 + lane;
      st_sc0(gp, rec);       // fast L2 copy
      AS(gp, rec);           // proven MALL copy (same bits)
      xraw = x[g * (TT * CC) + CC + pdfj];   // raw prefetch for t=1
    }

    int budget = SC0_BUDGET, streak = 0;

    for (int t = 1; t < TT; ++t) {
      unsigned long long* gin  = (t & 1) ? gb0 : gb1;
      unsigned long long* gout = (t & 1) ? gb1 : gb0;

      // poll own chunk: wave wv consumes producer WG cb==wv's 64 words
      const unsigned tg = (unsigned)(t - 1);
      unsigned long long* pa = gin + wv * 64 + lane;
      unsigned long long w = 0;
      bool ok = false;
      for (int s = 0; s < budget; ++s) {     // fast path: L2 (sc0) poll
        w = ld_sc0(pa);
        if ((unsigned)(w >> 32) == tg) { ok = true; break; }
        __builtin_amdgcn_s_sleep(1);
      }
      const bool allok = __all((int)ok);     // wave-uniform verdict
      if (!ok) {
        for (;;) {                           // round-0-proven agent fallback
          w = AL(pa);
          if ((unsigned)(w >> 32) == tg) break;
          __builtin_amdgcn_s_sleep(1);
        }
      }
      if (budget) { if (!allok) { if (++streak >= 4) budget = 0; } else streak = 0; }
      float pv = __uint_as_float((unsigned)w);

      // issue next-step emission raw load NOW: a full step of flight before
      // its use; already complete when the next poll's vmcnt(0) drains it.
      float xnew = 0.f;
      if (wv == 0 && t + 1 < TT)
        xnew = x[g * (TT * CC) + (t + 1) * CC + pdfj];

      // chunk max for the lagged renormalizer
      float cm = wave_max(pv);
      if (lane == 0) pmx[t & 1][wv] = cm;

      // matvec over own i-window: broadcast p via v_readlane (pure VALU)
      float q = 0.f;
      #pragma unroll
      for (int k = 0; k < 64; ++k) {
        float pk_ = rlane(pv, k);
        q = fmaf(pk_, Areg[k >> 2][k & 3], q);
      }
      prt[t & 1][wv * 64 + lane] = q;

      barrier_lds_only();   // LDS-ordering only; global loads keep flying

      if (wv == 0) {
        const float* pb = prt[t & 1];
        float qq = 0.f;
        #pragma unroll
        for (int w8 = 0; w8 < 8; ++w8) qq += pb[w8 * 64 + lane];
        float m = pmx[t & 1][0];
        #pragma unroll
        for (int w8 = 1; w8 < 8; ++w8) m = fmaxf(m, pmx[t & 1][w8]);
        float lm = __logf(m);
        float xv = clamp30(xraw);            // clamp deferred to use
        if (t < sl) {
          pcur = qq * __expf(xv - SHIFTC - lm);
          scale += SHIFTC + lm;
        }
        unsigned long long rec = pk((unsigned)t, pcur);
        unsigned long long* gp = gout + j0 + lane;
        st_sc0(gp, rec);     // fast L2 copy (same-XCD consumers)
        AS(gp, rec);         // MALL copy, identical bits (fallback + cross-XCD)
        xraw = xnew;
      }
    }
    if (wv == 0) {
      float part = wave_sum(pcur * __expf(lfj));
      if (lane == 0) {
        atomicAdd(wsf + WSF_DACC + g, part);
        if (cb == 0) wsf[WSF_DSCALE + g] = scale;
      }
    }
  } else {
    // ---------------- NUM (per-batch A, S=64), single wave, pure VALU -------
    const int b = blockIdx.x - NDEN;
    if (wv != 0) return;

    f4 Areg[16];   // lane holds exp(nA[i][lane]) for all i
    {
      const float* Ap = nA + b * SN * SN + lane;
      #pragma unroll
      for (int i = 0; i < 64; ++i)
        Areg[i >> 2][i & 3] = __expf(Ap[i * SN]);
      #pragma unroll
      for (int r = 0; r < 16; ++r)
        asm volatile("" : "+v"(Areg[r]));
    }
    const int   pdfj = npdf[b * SN + lane];
    const float lfj  = nlf[b * SN + lane];
    const int   sl   = seqlens[b];
    float xv0 = clamp30(x[b * (TT * CC) + pdfj]);
    float pcur = __expf(nls[b * SN + lane] + xv0 - SHIFTC);
    float scale = SHIFTC;
    // 2-deep RAW prefetch pipeline (clamp at use => waitcnt lands at use)
    float xr0 = x[b * (TT * CC) + CC + pdfj];
    float xr1 = (TT > 2) ? x[b * (TT * CC) + 2 * CC + pdfj] : 0.f;

    for (int t = 1; t < TT; ++t) {
      float xv = clamp30(xr0);
      xr0 = xr1;
      if (t + 2 < TT)
        xr1 = x[b * (TT * CC) + (t + 2) * CC + pdfj];
      float pold = pcur;
      float q = 0.f;
      #pragma unroll
      for (int i = 0; i < 64; ++i) {
        float pi = rlane(pold, i);
        q = fmaf(pi, Areg[i >> 2][i & 3], q);
      }
      float lm = __logf(wave_max(pold));
      if (t < sl) {
        pcur = q * __expf(xv - SHIFTC - lm);
        scale += SHIFTC + lm;
      }
    }
    float part = wave_sum(pcur * __expf(lfj));
    if (lane == 0) {
      wsf[WSF_NACC + b]   = part;
      wsf[WSF_NSCALE + b] = scale;
    }
  }
}

__global__ void fsm_final(const float* __restrict__ wsf, float* __restrict__ out) {
  const int tid = threadIdx.x;
  float v = 0.f;
  if (tid < 16)
    v = -(wsf[WSF_NSCALE + tid] + __logf(wsf[WSF_NACC + tid]));
  else if (tid < 32)
    v = (wsf[WSF_DSCALE + tid - 16] + __logf(wsf[WSF_DACC + tid - 16]));
  v = wave_sum(v);
  if (tid == 0) out[0] = v;  // loss = den_sum - num_sum
}

extern "C" void kernel_launch(void* const* d_in, const int* in_sizes, int n_in,
                              void* d_out, int out_size, void* d_ws, size_t ws_size,
                              hipStream_t stream) {
  const float* x    = (const float*)d_in[0];
  const int*   sql  = (const int*)d_in[1];
  const float* nA   = (const float*)d_in[2];
  const float* nls  = (const float*)d_in[3];
  const float* nlf  = (const float*)d_in[4];
  const int*   npdf = (const int*)d_in[5];
  const float* dA   = (const float*)d_in[6];
  const float* dls  = (const float*)d_in[7];
  const float* dlf  = (const float*)d_in[8];
  const int*   dpdf = (const int*)d_in[9];
  float* out = (float*)d_out;
  unsigned long long* p64 = (unsigned long long*)d_ws;
  float* wsf = (float*)d_ws;
  (void)in_sizes; (void)n_in; (void)out_size; (void)ws_size;

  // zero only the accumulators; tagged region relies on tag monotonicity
  hipMemsetAsync((char*)d_ws + 131072, 0, 256, stream);
  fsm_fwd<<<NDEN + BB, NTHR, 0, stream>>>(x, sql, nA, nls, nlf, npdf,
                                          dA, dls, dlf, dpdf, p64, wsf);
  fsm_final<<<1, 64, 0, stream>>>(wsf, out);
}

// Round 9
// 1182.643 us; speedup vs baseline: 3.4109x; 1.1449x over previous
//
#include <hip/hip_runtime.h>
#include <math.h>

#define BB 16
#define TT 500
#define CC 2048
#define SN 64
#define SD 512
#define NGRP 16         // den groups (1 batch each)
#define NDEN 128        // 16 groups * 8 column blocks
#define NTHR 512
#define SHIFTC 30.0f

// ws layout (known-safe footprint 131328 B):
//   bytes [0, 131072): u64 pg[2][16][512] -- (tag<<32)|float_bits
//   float index 32768+: DACC[16], DSCALE[16], NACC[16], NSCALE[16]
#define WSF_DACC   32768
#define WSF_DSCALE 32784
#define WSF_NACC   32800
#define WSF_NSCALE 32816

#define AL(p) __hip_atomic_load((p), __ATOMIC_RELAXED, __HIP_MEMORY_SCOPE_AGENT)
#define AS(p, v) __hip_atomic_store((p), (v), __ATOMIC_RELAXED, __HIP_MEMORY_SCOPE_AGENT)

typedef float f4 __attribute__((ext_vector_type(4)));

__device__ __forceinline__ float wave_max(float v) {
  #pragma unroll
  for (int off = 32; off > 0; off >>= 1) v = fmaxf(v, __shfl_xor(v, off, 64));
  return v;
}
__device__ __forceinline__ float wave_sum(float v) {
  #pragma unroll
  for (int off = 32; off > 0; off >>= 1) v += __shfl_xor(v, off, 64);
  return v;
}
__device__ __forceinline__ unsigned long long pk(unsigned tag, float v) {
  return ((unsigned long long)tag << 32) | (unsigned long long)__float_as_uint(v);
}
__device__ __forceinline__ float clamp30(float v) {
  return fminf(fmaxf(v, -30.f), 30.f);
}
__device__ __forceinline__ float rlane(float v, int k) {
  return __uint_as_float(__builtin_amdgcn_readlane(__float_as_uint(v), k));
}

// LDS-only barrier: __syncthreads() drains vmcnt(0), serializing in-flight
// global prefetches; LDS producer/consumer ordering needs only lgkmcnt.
__device__ __forceinline__ void barrier_lds_only() {
  asm volatile("s_waitcnt lgkmcnt(0)" ::: "memory");
  __builtin_amdgcn_s_barrier();
  asm volatile("" ::: "memory");
}

__global__ __launch_bounds__(NTHR, 1) void fsm_fwd(
    const float* __restrict__ x, const int* __restrict__ seqlens,
    const float* __restrict__ nA, const float* __restrict__ nls,
    const float* __restrict__ nlf, const int* __restrict__ npdf,
    const float* __restrict__ dA, const float* __restrict__ dls,
    const float* __restrict__ dlf, const int* __restrict__ dpdf,
    unsigned long long* __restrict__ p64, float* __restrict__ wsf)
{
  __shared__ float prt[2][8][64];    // [t-parity][i-window wave][col]
  __shared__ float pmx[2][8];        // [t-parity][i-window wave]
  const int tid = threadIdx.x;
  const int lane = tid & 63, wv = tid >> 6;

  if (blockIdx.x < NDEN) {
    // ---------------- DEN (shared A, S=512), 1 batch per group --------------
    // g = bid & 15: all 8 column-block WGs of a group share bid%8 => one XCD
    // under round-robin dispatch; FETCH evidence (r0..r8) shows the exchange
    // polls are L2-hits (no EA traffic beyond compulsory x reads).
    const int g  = blockIdx.x & 15;     // group == batch
    const int cb = blockIdx.x >> 4;     // column block (0..7)
    const int j0 = cb * 64;

    // A in registers: lane holds exp(A[wv*64+k][j0+lane])
    f4 Areg[16];
    {
      const float* Ap = dA + (wv * 64) * SD + j0 + lane;
      #pragma unroll
      for (int k = 0; k < 64; ++k)
        Areg[k >> 2][k & 3] = __expf(Ap[k * SD]);
      #pragma unroll
      for (int r = 0; r < 16; ++r)
        asm volatile("" : "+v"(Areg[r]));
    }

    unsigned long long* gb0 = p64 + (size_t)g * SD;              // buf 0
    unsigned long long* gb1 = p64 + (size_t)(NGRP + g) * SD;     // buf 1

    // DISTRIBUTED epilogue ownership: wave wv's lanes 0..7 own columns
    // j0 + 8*wv .. j0 + 8*wv + 7. Identical per-column arithmetic order to
    // the r0 wave0 epilogue (ascending w8 adds / maxes) => bit-exact (r7
    // passed with absmax 0.0). Store issues from 8 waves in parallel and
    // ~350cy earlier than the wave0-serial version.
    const int  oc   = j0 + 8 * wv + (lane & 7);   // owner column (lane<8)
    const bool own  = (lane < 8);
    int   pdfo = 0, sl = 0;
    float lfo = 0.f, lso = 0.f, pcur = 0.f, scale = SHIFTC, xraw = 0.f;
    if (own) {
      pdfo = dpdf[oc];
      lfo  = dlf[oc];
      lso  = dls[oc];
      sl   = seqlens[g];
      float xv = clamp30(x[(size_t)g * (TT * CC) + pdfo]);
      pcur = __expf(lso + xv - SHIFTC);
      AS(gb0 + oc, pk(0u, pcur));
      xraw = x[(size_t)g * (TT * CC) + CC + pdfo];   // raw prefetch for t=1
    }

    for (int t = 1; t < TT; ++t) {
      unsigned long long* gin  = (t & 1) ? gb0 : gb1;
      unsigned long long* gout = (t & 1) ? gb1 : gb0;
      const int par = t & 1;

      // poll own chunk: wave wv consumes the 64 words produced by WG cb==wv.
      // Pure spin (no s_sleep): loads are L2-hits; the sleep's 64-cy quantum
      // only added detect latency.
      const unsigned tg = (unsigned)(t - 1);
      unsigned long long* pa = gin + wv * 64 + lane;
      unsigned long long w;
      for (;;) {
        w = AL(pa);
        if ((unsigned)(w >> 32) == tg) break;
      }
      float pv = __uint_as_float((unsigned)w);

      // chunk max for the lagged renormalizer
      float cm = wave_max(pv);
      if (lane == 0) pmx[par][wv] = cm;

      // matvec over own i-window: broadcast p via v_readlane (pure VALU)
      float q = 0.f;
      #pragma unroll
      for (int k = 0; k < 64; ++k) {
        float pk_ = rlane(pv, k);
        q = fmaf(pk_, Areg[k >> 2][k & 3], q);
      }
      prt[par][wv][lane] = q;

      barrier_lds_only();   // LDS-ordering only; global loads keep flying

      // distributed epilogue: 8 columns per wave, lanes 0..7
      if (own) {
        float m = pmx[par][0];
        #pragma unroll
        for (int w8 = 1; w8 < 8; ++w8) m = fmaxf(m, pmx[par][w8]);
        float lm = __logf(m);
        float qq = 0.f;
        #pragma unroll
        for (int w8 = 0; w8 < 8; ++w8) qq += prt[par][w8][8 * wv + (lane & 7)];
        float xv = clamp30(xraw);          // clamp deferred to use
        if (t < sl) {
          pcur = qq * __expf(xv - SHIFTC - lm);
          scale += SHIFTC + lm;
        }
        AS(gout + oc, pk((unsigned)t, pcur));
        if (t + 1 < TT)                    // raw emission prefetch, 1 step out
          xraw = x[(size_t)g * (TT * CC) + (size_t)(t + 1) * CC + pdfo];
      }
      // all waves go straight to polling t+1 (prt/pmx double-buffered)
    }

    {
      float v = own ? pcur * __expf(lfo) : 0.f;
      float part = wave_sum(v);
      if (lane == 0)
        atomicAdd(wsf + WSF_DACC + g, part);
      if (cb == 0 && wv == 0 && lane == 0)
        wsf[WSF_DSCALE + g] = scale;
    }
  } else {
    // ---------------- NUM (per-batch A, S=64), single wave, pure VALU -------
    const int b = blockIdx.x - NDEN;
    if (wv != 0) return;

    f4 Areg[16];   // lane holds exp(nA[i][lane]) for all i
    {
      const float* Ap = nA + b * SN * SN + lane;
      #pragma unroll
      for (int i = 0; i < 64; ++i)
        Areg[i >> 2][i & 3] = __expf(Ap[i * SN]);
      #pragma unroll
      for (int r = 0; r < 16; ++r)
        asm volatile("" : "+v"(Areg[r]));
    }
    const int   pdfj = npdf[b * SN + lane];
    const float lfj  = nlf[b * SN + lane];
    const int   sl   = seqlens[b];
    float xv0 = clamp30(x[(size_t)b * (TT * CC) + pdfj]);
    float pcur = __expf(nls[b * SN + lane] + xv0 - SHIFTC);
    float scale = SHIFTC;
    // 2-deep RAW prefetch pipeline (clamp at use => waitcnt lands at use)
    float xr0 = x[(size_t)b * (TT * CC) + CC + pdfj];
    float xr1 = (TT > 2) ? x[(size_t)b * (TT * CC) + 2 * CC + pdfj] : 0.f;

    for (int t = 1; t < TT; ++t) {
      float xv = clamp30(xr0);
      xr0 = xr1;
      if (t + 2 < TT)
        xr1 = x[(size_t)b * (TT * CC) + (size_t)(t + 2) * CC + pdfj];
      float pold = pcur;
      float q = 0.f;
      #pragma unroll
      for (int i = 0; i < 64; ++i) {
        float pi = rlane(pold, i);
        q = fmaf(pi, Areg[i >> 2][i & 3], q);
      }
      float lm = __logf(wave_max(pold));
      if (t < sl) {
        pcur = q * __expf(xv - SHIFTC - lm);
        scale += SHIFTC + lm;
      }
    }
    float part = wave_sum(pcur * __expf(lfj));
    if (lane == 0) {
      wsf[WSF_NACC + b]   = part;
      wsf[WSF_NSCALE + b] = scale;
    }
  }
}

__global__ void fsm_final(const float* __restrict__ wsf, float* __restrict__ out) {
  const int tid = threadIdx.x;
  float v = 0.f;
  if (tid < 16)
    v = -(wsf[WSF_NSCALE + tid] + __logf(wsf[WSF_NACC + tid]));
  else if (tid < 32)
    v = (wsf[WSF_DSCALE + tid - 16] + __logf(wsf[WSF_DACC + tid - 16]));
  v = wave_sum(v);
  if (tid == 0) out[0] = v;  // loss = den_sum - num_sum
}

extern "C" void kernel_launch(void* const* d_in, const int* in_sizes, int n_in,
                              void* d_out, int out_size, void* d_ws, size_t ws_size,
                              hipStream_t stream) {
  const float* x    = (const float*)d_in[0];
  const int*   sql  = (const int*)d_in[1];
  const float* nA   = (const float*)d_in[2];
  const float* nls  = (const float*)d_in[3];
  const float* nlf  = (const float*)d_in[4];
  const int*   npdf = (const int*)d_in[5];
  const float* dA   = (const float*)d_in[6];
  const float* dls  = (const float*)d_in[7];
  const float* dlf  = (const float*)d_in[8];
  const int*   dpdf = (const int*)d_in[9];
  float* out = (float*)d_out;
  unsigned long long* p64 = (unsigned long long*)d_ws;
  float* wsf = (float*)d_ws;
  (void)in_sizes; (void)n_in; (void)out_size; (void)ws_size;

  // zero only the accumulators; tagged region relies on tag monotonicity
  hipMemsetAsync((char*)d_ws + 131072, 0, 256, stream);
  fsm_fwd<<<NDEN + BB, NTHR, 0, stream>>>(x, sql, nA, nls, nlf, npdf,
                                          dA, dls, dlf, dpdf, p64, wsf);
  fsm_final<<<1, 64, 0, stream>>>(wsf, out);
}